// Round 1
// baseline (314.383 us; speedup 1.0000x reference)
//
#include <hip/hip_runtime.h>
#include <hip/hip_bf16.h>
#include <stdint.h>

// Problem constants (from reference)
#define O_DIM   4096
#define I_DIM   2048
#define M_DENSE 8192
#define K_DENSE 4096
#define N_TOK   4096
#define K_ACT   2048

typedef __bf16 bf16x8 __attribute__((ext_vector_type(8)));
typedef float  f32x4  __attribute__((ext_vector_type(4)));

// round-to-nearest-even fp32 -> bf16 bits
__device__ __forceinline__ unsigned short f2bf(float f) {
    unsigned u = __builtin_bit_cast(unsigned, f);
    unsigned r = (u + 0x7FFFu + ((u >> 16) & 1u)) >> 16;
    return (unsigned short)r;
}

// async global->LDS, 16 bytes per lane. lds must be wave-uniform base;
// HW adds lane*16 (guide §5: wave-uniform base + lane*size).
__device__ __forceinline__ void load16(const unsigned short* g, unsigned short* l) {
    __builtin_amdgcn_global_load_lds(
        (__attribute__((address_space(1))) void*)(g),
        (__attribute__((address_space(3))) void*)(l),
        16, 0, 0);
}

// inv[c] = j such that idx[j] == c, else -1. idx sorted unique.
__global__ void build_inv(const int* __restrict__ idx, int* __restrict__ inv) {
    int c = blockIdx.x * blockDim.x + threadIdx.x;
    if (c >= K_DENSE) return;
    int lo = 0, hi = K_ACT;
    while (lo < hi) { int mid = (lo + hi) >> 1; if (idx[mid] < c) lo = mid + 1; else hi = mid; }
    inv[c] = (lo < K_ACT && idx[lo] == c) ? lo : -1;
}

// A2[o][j] (bf16 bits, [O_DIM x K_ACT] row-major): compressed weight remapped
// to active-column coordinates. One thread per (o, dense-group-of-4). Every
// A2 element is written exactly once -> no zero-init required.
__global__ void decompress_w(const float* __restrict__ weight,
                             const int* __restrict__ metadata,
                             const int* __restrict__ inv,
                             unsigned short* __restrict__ A2) {
    int gid = blockIdx.x * blockDim.x + threadIdx.x;  // O_DIM * I_DIM/2 threads
    int o = gid >> 10;           // I_DIM/2 = 1024 groups per row
    int g = gid & 1023;
    size_t base = (size_t)o * I_DIM + 2 * g;
    int2   meta = *(const int2*)(metadata + base);
    float2 wv   = *(const float2*)(weight + base);
    int cbase = g * 4;
    size_t arow = (size_t)o * K_ACT;
#pragma unroll
    for (int c4 = 0; c4 < 4; ++c4) {
        int j = inv[cbase + c4];
        if (j >= 0) {
            float val = (meta.x == c4) ? wv.x : ((meta.y == c4) ? wv.y : 0.0f);
            A2[arow + j] = f2bf(val);
        }
    }
}

// input fp32 [N_TOK x K_ACT] -> bf16 bits, same layout (this IS B^T: [n][k])
__global__ void cast_b(const float4* __restrict__ in, unsigned short* __restrict__ outb) {
    int i = blockIdx.x * blockDim.x + threadIdx.x;  // N_TOK*K_ACT/4 threads
    float4 v = in[i];
    ushort4 u;
    u.x = f2bf(v.x); u.y = f2bf(v.y); u.z = f2bf(v.z); u.w = f2bf(v.w);
    *(ushort4*)(outb + (size_t)i * 4) = u;
}

// GEMM: C[o][t] = sum_j A2[o][j] * Bt[t][j]; rows scattered to out[indices[o]].
// M=4096, N=4096, K=2048. 128x128 tile, BK=32, 4 waves, 16x16x32 bf16 MFMA.
__global__ void gemm_scatter(const unsigned short* __restrict__ A,
                             const unsigned short* __restrict__ Bt,
                             const int* __restrict__ indices,
                             float* __restrict__ out) {
    constexpr int N = N_TOK, K = K_ACT;
    constexpr int TM = 128, TN = 128, BK = 32;
    __shared__ alignas(16) unsigned short sA[TM * BK];
    __shared__ alignas(16) unsigned short sB[TN * BK];

    const int t    = threadIdx.x;       // 0..255
    const int wave = t >> 6;            // 0..3
    const int lane = t & 63;
    const int m0 = blockIdx.y * TM;
    const int n0 = blockIdx.x * TN;

    // staging: q in {0,1}; flat = q*256 + t; LDS bytes [flat*16, +16)
    // = row (flat>>2) of tile, k-segment (flat&3)*8 elements.
    const int fa0 = t, fa1 = t + 256;
    const unsigned short* gA0 = A  + (size_t)(m0 + (fa0 >> 2)) * K + (fa0 & 3) * 8;
    const unsigned short* gA1 = A  + (size_t)(m0 + (fa1 >> 2)) * K + (fa1 & 3) * 8;
    const unsigned short* gB0 = Bt + (size_t)(n0 + (fa0 >> 2)) * K + (fa0 & 3) * 8;
    const unsigned short* gB1 = Bt + (size_t)(n0 + (fa1 >> 2)) * K + (fa1 & 3) * 8;

    // wave-uniform LDS bases (elements): q*2048 + wave*512
    unsigned short* lA0 = sA + wave * 512;
    unsigned short* lA1 = sA + 2048 + wave * 512;
    unsigned short* lB0 = sB + wave * 512;
    unsigned short* lB1 = sB + 2048 + wave * 512;

    const int wm   = (wave >> 1) * 64;  // wave's 64x64 quadrant
    const int wn   = (wave & 1) * 64;
    const int quad = lane >> 4;
    const int lr   = lane & 15;
    const int kq   = quad * 8;

    f32x4 acc[4][4] = {};

    for (int kk = 0; kk < K; kk += BK) {
        __syncthreads();   // previous compute done before overwriting LDS
        load16(gA0 + kk, lA0);
        load16(gA1 + kk, lA1);
        load16(gB0 + kk, lB0);
        load16(gB1 + kk, lB1);
        __syncthreads();   // compiler drains vmcnt before s_barrier

        bf16x8 af[4], bf[4];
#pragma unroll
        for (int mi = 0; mi < 4; ++mi)
            af[mi] = *(const bf16x8*)(sA + (wm + mi * 16 + lr) * BK + kq);
#pragma unroll
        for (int ni = 0; ni < 4; ++ni)
            bf[ni] = *(const bf16x8*)(sB + (wn + ni * 16 + lr) * BK + kq);
#pragma unroll
        for (int mi = 0; mi < 4; ++mi)
#pragma unroll
            for (int ni = 0; ni < 4; ++ni)
                acc[mi][ni] = __builtin_amdgcn_mfma_f32_16x16x32_bf16(
                    af[mi], bf[ni], acc[mi][ni], 0, 0, 0);
    }

    // epilogue: D lane layout col=lane&15, row=quad*4+reg (m91-verified)
#pragma unroll
    for (int mi = 0; mi < 4; ++mi) {
#pragma unroll
        for (int r = 0; r < 4; ++r) {
            int gm = m0 + wm + mi * 16 + quad * 4 + r;
            int orow = indices[gm];
            float* op = out + (size_t)orow * N + n0 + wn + lr;
#pragma unroll
            for (int ni = 0; ni < 4; ++ni)
                op[ni * 16] = acc[mi][ni][r];
        }
    }
}

extern "C" void kernel_launch(void* const* d_in, const int* in_sizes, int n_in,
                              void* d_out, int out_size, void* d_ws, size_t ws_size,
                              hipStream_t stream) {
    const float* input    = (const float*)d_in[0];
    const int*   idx      = (const int*)d_in[1];
    const float* weight   = (const float*)d_in[2];
    const int*   indices  = (const int*)d_in[3];
    const int*   metadata = (const int*)d_in[4];
    float* out = (float*)d_out;

    // workspace layout: A2 (16 MB) | Bbt (16 MB) | inv (16 KB)
    unsigned short* A2  = (unsigned short*)d_ws;
    unsigned short* Bbt = (unsigned short*)((char*)d_ws + (size_t)(16 << 20));
    int*            inv = (int*)((char*)d_ws + (size_t)(32 << 20));

    // zero full output (inactive rows must be 0; harness poisons d_out)
    hipMemsetAsync(out, 0, (size_t)out_size * sizeof(float), stream);

    build_inv<<<K_DENSE / 256, 256, 0, stream>>>(idx, inv);
    decompress_w<<<(O_DIM * (I_DIM / 2)) / 256, 256, 0, stream>>>(weight, metadata, inv, A2);
    cast_b<<<(N_TOK * K_ACT / 4) / 256, 256, 0, stream>>>((const float4*)input, Bbt);

    dim3 grid(N_TOK / 128, O_DIM / 128);  // (32, 32)
    gemm_scatter<<<grid, 256, 0, stream>>>(A2, Bbt, indices, out);
}